// Round 13
// baseline (4763.194 us; speedup 1.0000x reference)
//
#include <hip/hip_runtime.h>
#include <stdint.h>

#define TSTEPS 512

typedef __attribute__((ext_vector_type(8))) _Float16 half8;
typedef __attribute__((ext_vector_type(4))) _Float16 half4;
typedef __attribute__((ext_vector_type(4))) float f32x4;
typedef __attribute__((ext_vector_type(4))) float float4v;
typedef unsigned long long u64;

static __device__ __forceinline__ float sigm(float x) { return 1.f / (1.f + __expf(-x)); }
static __device__ __forceinline__ float tanh_(float x) {
  x = fminf(15.f, fmaxf(-15.f, x));
  float e = __expf(-2.f * x);
  return (1.f - e) / (1.f + e);
}
static __device__ __forceinline__ half8 ld8(const _Float16* p) { return *(const half8*)p; }
static __device__ __forceinline__ f32x4 MFMA(half8 a, half8 b, f32x4 c) {
  return __builtin_amdgcn_mfma_f32_16x16x32_f16(a, b, c, 0, 0, 0);
}

// ---- MALL primitives (agent scope; proven r4/r5/r8/r12) ----
static __device__ __forceinline__ unsigned aadd(unsigned* p) {
  return __hip_atomic_fetch_add(p, 1u, __ATOMIC_RELAXED, __HIP_MEMORY_SCOPE_AGENT);
}
static __device__ __forceinline__ unsigned ald(const unsigned* p) {
  return __hip_atomic_load(p, __ATOMIC_RELAXED, __HIP_MEMORY_SCOPE_AGENT);
}
static __device__ __forceinline__ void ast(unsigned* p, unsigned v) {
  __hip_atomic_store(p, v, __ATOMIC_RELAXED, __HIP_MEMORY_SCOPE_AGENT);
}
struct U64x2 { u64 x, y; };
static __device__ __forceinline__ half8 ld_msg16(const u64* p) {
  u64 a = __hip_atomic_load(p,     __ATOMIC_RELAXED, __HIP_MEMORY_SCOPE_AGENT);
  u64 b = __hip_atomic_load(p + 1, __ATOMIC_RELAXED, __HIP_MEMORY_SCOPE_AGENT);
  U64x2 u{a, b};
  return __builtin_bit_cast(half8, u);
}
static __device__ __forceinline__ void st_msg(u64* p, u64 v) {
  __hip_atomic_store(p, v, __ATOMIC_RELAXED, __HIP_MEMORY_SCOPE_AGENT);
}
static __device__ __forceinline__ void wait_flags(const unsigned* line, unsigned tag) {
  const unsigned* p = line + (threadIdx.x & 31);
  while (!__all(ald(p) >= tag))
    __builtin_amdgcn_s_sleep(1);
  asm volatile("" ::: "memory");
}
static __device__ __forceinline__ void wait_blk(const unsigned* r) {
  while (ald(r) < 32u) __builtin_amdgcn_s_sleep(4);
  asm volatile("" ::: "memory");
}
// f16 write-through to MALL (cross-XCD visible without dirty-L2 hazard)
static __device__ __forceinline__ void st_f16_wt(_Float16* p, float v) {
  unsigned u = (unsigned)(unsigned short)__builtin_bit_cast(unsigned short, (_Float16)v);
  asm volatile("global_store_short %0, %1, off sc0 sc1" :: "v"(p), "v"(u) : "memory");
}

// ---------------- f32 -> f16 conversion / init (r8-identical) ----------------
__global__ __launch_bounds__(256) void kconv(
    const float* __restrict__ xs, const float* __restrict__ wih,
    const float* __restrict__ wxh, const float* __restrict__ whhf,
    const float* __restrict__ wrf, const float* __restrict__ h0,
    _Float16* __restrict__ xs_h, _Float16* __restrict__ wcat,
    _Float16* __restrict__ whh, _Float16* __restrict__ wr,
    _Float16* __restrict__ hx) {
  const long n1 = 8388608;   // xs / 4
  const long n2 = 1048576;   // wcat / 4
  const long n3 = 786432;    // whh / 4
  const long n4 = 262144;    // wr / 4
  const long n5 = 16384;     // h0 / 4 -> hx parity-0
  const long total = n1 + n2 + n3 + n4 + n5;
  for (long i = (long)blockIdx.x * 256 + threadIdx.x; i < total; i += (long)gridDim.x * 256) {
    const float* s; _Float16* d;
    if (i < n1) { s = xs + i * 4; d = xs_h + i * 4; }
    else if (i < n1 + n2) {
      long e = (i - n1) * 4;
      s = (e < 3145728) ? (wih + e) : (wxh + (e - 3145728));
      d = wcat + e;
    } else if (i < n1 + n2 + n3) { long e = (i - n1 - n2) * 4; s = whhf + e; d = whh + e; }
    else if (i < n1 + n2 + n3 + n4) { long e = (i - n1 - n2 - n3) * 4; s = wrf + e; d = wr + e; }
    else { long e = (i - n1 - n2 - n3 - n4) * 4; s = h0 + e; d = hx + e; }
    float4v v = *(const float4v*)s;
    half4 o = { (_Float16)v.x, (_Float16)v.y, (_Float16)v.z, (_Float16)v.w };
    *(half4*)d = o;
  }
}

// ---------------- gemm half: throttled just-in-time tile production ----------------
static __device__ void run_gemm(
    int tid, int gw,
    const _Float16* __restrict__ X, const _Float16* __restrict__ W,
    const float* __restrict__ b_ih, const float* __restrict__ b_xh,
    _Float16* __restrict__ C, unsigned* __restrict__ ready,
    const unsigned* __restrict__ recstep,
    _Float16* As, _Float16* Bs) {
  const int half = tid >> 8;         // two independent 256-thread tile engines
  const int htid = tid & 255;
  const int lane = htid & 63;
  const int w4 = htid >> 6;
  const int wm = (w4 >> 1) * 64, wn = (w4 & 1) * 64;
  const int arow = htid >> 2;
  const int kk8 = (htid & 3) * 8;
  const int fr = lane & 15, fq = lane >> 4;
  _Float16* as = As + half * 5120;
  _Float16* bs = Bs + half * 5120;
  const f32x4 zero = {0.f, 0.f, 0.f, 0.f};

  for (int i = 0; i < 32; ++i) {
    const int j = gw * 2 + half + 256 * i;   // bm-major job order (bn fixed/engine)
    const int bm = j >> 5, bn = j & 31;
    const int rb = bm * 128, cb = bn * 128;
    // throttle: stay <=16 blocks (~256us) ahead of the recurrence to spread
    // gemm's memory traffic (r12: bursty gemm inflated exchange latency +288us)
    {
      const int need = 2 * bm - 32;
      if (need > 0) {
        if (htid == 0)
          while ((int)ald(recstep) < need) __builtin_amdgcn_s_sleep(16);
        __syncthreads();
      }
    }
    f32x4 acc[4][4];
    #pragma unroll
    for (int a = 0; a < 4; a++)
      #pragma unroll
      for (int b = 0; b < 4; b++) acc[a][b] = zero;
    for (int kt = 0; kt < 1024; kt += 32) {
      __syncthreads();
      #pragma unroll
      for (int jj = 0; jj < 2; jj++) {
        int r = jj * 64 + arow;
        *(half8*)(as + r * 40 + kk8) = ld8(X + (size_t)(rb + r) * 1024 + kt + kk8);
        *(half8*)(bs + r * 40 + kk8) = ld8(W + (size_t)(cb + r) * 1024 + kt + kk8);
      }
      __syncthreads();
      half8 af[4], bfr[4];
      #pragma unroll
      for (int q = 0; q < 4; q++) {
        af[q]  = *(const half8*)(as + (wm + q * 16 + fr) * 40 + fq * 8);
        bfr[q] = *(const half8*)(bs + (wn + q * 16 + fr) * 40 + fq * 8);
      }
      #pragma unroll
      for (int mi = 0; mi < 4; mi++)
        #pragma unroll
        for (int ni = 0; ni < 4; ni++)
          acc[mi][ni] = MFMA(af[mi], bfr[ni], acc[mi][ni]);
    }
    #pragma unroll
    for (int mi = 0; mi < 4; mi++)
      #pragma unroll
      for (int ni = 0; ni < 4; ni++) {
        int col = cb + wn + ni * 16 + fr;
        float bias = (col < 3072) ? b_ih[col] : b_xh[col - 3072];
        #pragma unroll
        for (int r = 0; r < 4; r++) {
          int row = rb + wm + mi * 16 + fq * 4 + r;
          st_f16_wt(C + (size_t)row * 4096 + col, acc[mi][ni][r] + bias);
        }
      }
    asm volatile("s_waitcnt vmcnt(0)" ::: "memory");   // C at MALL
    __syncthreads();
    if (htid == 0) (void)aadd(&ready[bm]);
  }
}

// ---------------- rec half: r8-proven protocol + xg ready-gating ----------------
#define RP 20
#define TP (16 * RP)

static __device__ void run_rec(
    int tid, int bid,
    const _Float16* __restrict__ xgh, const float* __restrict__ ms,
    const _Float16* __restrict__ whh, const _Float16* __restrict__ wr,
    const float* __restrict__ b_hh, const float* __restrict__ b_r,
    const float* __restrict__ h0,
    u64* __restrict__ hmsg, u64* __restrict__ rhmsg,
    float* __restrict__ out, unsigned* __restrict__ ctr,
    unsigned* __restrict__ ready, float* red) {
  const int lane = tid & 63, w = tid >> 6;
  const int fr = lane & 15, fq = lane >> 4;
  const int g = bid >> 5;
  const int slot = bid & 31;
  const int colbase = slot * 32;
  unsigned* flagA = ctr + (g * 2 + 0) * 32;   // rh(t) published => t+1
  unsigned* flagB = ctr + (g * 2 + 1) * 32;   // h(t) published  => t

  // weight fragments -> registers (unified VGPR/AGPR file keeps them resident)
  half8 wA[6][4], wB[2][4];
  #pragma unroll
  for (int nt = 0; nt < 6; nt++)
    #pragma unroll
    for (int ks = 0; ks < 4; ks++)
      wA[nt][ks] = ld8(whh + (size_t)((nt >> 1) * 1024 + colbase + (nt & 1) * 16 + fr) * 1024
                            + w * 128 + ks * 32 + fq * 8);
  #pragma unroll
  for (int nt = 0; nt < 2; nt++)
    #pragma unroll
    for (int ks = 0; ks < 4; ks++)
      wB[nt][ks] = ld8(wr + (size_t)(colbase + nt * 16 + fr) * 1024
                           + w * 128 + ks * 32 + fq * 8);

  const int b = tid >> 5, cc = tid & 31;
  const int gc = colbase + cc;
  const int gm = g * 16 + b;
  const float bhr = b_hh[gc], bhz = b_hh[1024 + gc], bhe = b_hh[2048 + gc];
  const float brr = b_r[gc];
  float hreg = h0[(size_t)gm * 1024 + gc];

  const u64* hcons = hmsg  + (g * 16 + fr) * 256 + w * 32 + fq * 2;
  const u64* rcons = rhmsg + (g * 16 + fr) * 256 + w * 32 + fq * 2;
  u64* hprod = hmsg  + gm * 256 + (gc >> 2);
  u64* rprod = rhmsg + gm * 256 + (gc >> 2);

  const f32x4 zero = {0.f, 0.f, 0.f, 0.f};

  // gated initial prefetch (needs xgh block 0)
  float pxr, pxz, pxe, pxh, ptm;
  wait_blk(&ready[0]);
  {
    const _Float16* xp = xgh + (size_t)gm * 4096;
    pxr = (float)xp[gc]; pxz = (float)xp[1024 + gc];
    pxe = (float)xp[2048 + gc]; pxh = (float)xp[3072 + gc];
    ptm = tanh_(ms[(size_t)gm * 1024 + gc]);
  }

  #pragma clang loop unroll(disable)
  for (int t = 0; t < TSTEPS; t++) {
    const int ph = t & 1;
    // ======== phase A: h(t) -> gates; publish rh(t)
    wait_flags(flagB, (unsigned)t);
    half8 av[4];
    #pragma unroll
    for (int ks = 0; ks < 4; ks++)
      av[ks] = ld_msg16(hcons + ph * 16384 + ks * 8);
    f32x4 accA[6];
    #pragma unroll
    for (int nt = 0; nt < 6; nt++) accA[nt] = zero;
    #pragma unroll
    for (int ks = 0; ks < 4; ks++)
      #pragma unroll
      for (int nt = 0; nt < 6; nt++)
        accA[nt] = MFMA(av[ks], wA[nt][ks], accA[nt]);
    #pragma unroll
    for (int nt = 0; nt < 6; nt++)
      #pragma unroll
      for (int r = 0; r < 4; r++)
        red[(w * 6 + nt) * TP + (fq * 4 + r) * RP + fr] = accA[nt][r];
    __syncthreads();                            // S1
    float sr = pxr + bhr, sz = pxz + bhz, se = pxe + bhe;
    {
      const int boff = b * RP + (cc & 15) + (cc >> 4) * TP;
      #pragma unroll
      for (int w8 = 0; w8 < 8; w8++) {
        const float* rp = red + w8 * 6 * TP + boff;
        sr += rp[0]; sz += rp[2 * TP]; se += rp[4 * TP];
      }
    }
    float rg = sigm(sr);
    float zz = sigm(sz), ee = sigm(se);
    {
      float rv = rg * hreg;
      unsigned us = (unsigned)(unsigned short)__builtin_bit_cast(unsigned short, (_Float16)rv);
      unsigned v01 = us | (((unsigned)__shfl_down((int)us, 1) & 0xFFFFu) << 16);
      unsigned v23 = (unsigned)__shfl_down((int)v01, 2);
      if (!(cc & 3))
        st_msg(rprod + ph * 16384, ((u64)v23 << 32) | (u64)v01);
    }
    asm volatile("s_waitcnt vmcnt(0)" ::: "memory");
    __syncthreads();                            // S2: rh acked (+red guard)
    if (tid == 0)
      ast(flagA + slot, (unsigned)(t + 1));
    // overlap window: gated prefetch of next step's xg/ms
    float nxr = 0.f, nxz = 0.f, nxe = 0.f, nxh = 0.f, ntm = 0.f;
    if (t + 1 < TSTEPS) {
      wait_blk(&ready[(t + 1) >> 1]);
      const _Float16* xp = xgh + (size_t)((t + 1) * 64 + gm) * 4096;
      nxr = (float)xp[gc]; nxz = (float)xp[1024 + gc];
      nxe = (float)xp[2048 + gc]; nxh = (float)xp[3072 + gc];
      ntm = tanh_(ms[(size_t)(t + 1) * 65536 + gm * 1024 + gc]);
    }
    wait_flags(flagA, (unsigned)(t + 1));

    // ======== phase B: rh(t) -> hhat; h update; publish h(t+1)
    half8 bv[4];
    #pragma unroll
    for (int ks = 0; ks < 4; ks++)
      bv[ks] = ld_msg16(rcons + ph * 16384 + ks * 8);
    f32x4 accB[2];
    #pragma unroll
    for (int nt = 0; nt < 2; nt++) accB[nt] = zero;
    #pragma unroll
    for (int ks = 0; ks < 4; ks++)
      #pragma unroll
      for (int nt = 0; nt < 2; nt++)
        accB[nt] = MFMA(bv[ks], wB[nt][ks], accB[nt]);
    #pragma unroll
    for (int nt = 0; nt < 2; nt++)
      #pragma unroll
      for (int r = 0; r < 4; r++)
        red[(w * 6 + nt) * TP + (fq * 4 + r) * RP + fr] = accB[nt][r];
    __syncthreads();                            // S3
    float s = pxh + brr;
    {
      const int boff = b * RP + (cc & 15) + (cc >> 4) * TP;
      #pragma unroll
      for (int w8 = 0; w8 < 8; w8++) s += red[w8 * 6 * TP + boff];
    }
    float hh = tanh_(s);
    float hn = zz * hreg + (1.f - zz) * hh + ee * ptm;
    hreg = hn;
    {
      unsigned us = (unsigned)(unsigned short)__builtin_bit_cast(unsigned short, (_Float16)hn);
      unsigned v01 = us | (((unsigned)__shfl_down((int)us, 1) & 0xFFFFu) << 16);
      unsigned v23 = (unsigned)__shfl_down((int)v01, 2);
      if (!(cc & 3))
        st_msg(hprod + (ph ^ 1) * 16384, ((u64)v23 << 32) | (u64)v01);
    }
    asm volatile("s_waitcnt vmcnt(0)" ::: "memory");
    __syncthreads();                            // S4: h acked (+red guard)
    if (tid == 0)
      ast(flagB + slot, (unsigned)(t + 1));
    __builtin_nontemporal_store(hn, out + (size_t)t * 65536 + gm * 1024 + gc);
    pxr = nxr; pxz = nxz; pxe = nxe; pxh = nxh; ptm = ntm;
  }
  out[(size_t)TSTEPS * 65536 + gm * 1024 + gc] = hreg;
}

// ---------------- fused kernel: 128 rec wgs + 128 gemm wgs ----------------
__global__ __launch_bounds__(512, 2) void krec(
    const _Float16* __restrict__ xgh_c, const float* __restrict__ ms,
    const _Float16* __restrict__ whh, const _Float16* __restrict__ wr,
    const float* __restrict__ b_hh, const float* __restrict__ b_r,
    const float* __restrict__ h0,
    u64* __restrict__ hmsg, u64* __restrict__ rhmsg,
    float* __restrict__ out, unsigned* __restrict__ ctr,
    const _Float16* __restrict__ X, const _Float16* __restrict__ W,
    const float* __restrict__ b_ih, const float* __restrict__ b_xh,
    _Float16* __restrict__ xgh_w) {
  __shared__ float red[48 * TP];                 // 60 KiB (rec)
  __shared__ _Float16 As[2 * 5120], Bs[2 * 5120]; // 40 KiB (gemm)
  const int tid = threadIdx.x;
  const int bid = (int)blockIdx.x;
  unsigned* ready = ctr + 256;                   // per-bm-block counters
  // rec group 0's flagB[0] doubles as the recurrence step counter
  const unsigned* recstep = ctr + 32;

  if (bid < 128) {
    run_rec(tid, bid, xgh_c, ms, whh, wr, b_hh, b_r, h0,
            hmsg, rhmsg, out, ctr, ready, red);
  } else {
    run_gemm(tid, bid - 128, X, W, b_ih, b_xh, xgh_w, ready, recstep, As, Bs);
  }
}

extern "C" void kernel_launch(void* const* d_in, const int* in_sizes, int n_in,
                              void* d_out, int out_size, void* d_ws, size_t ws_size,
                              hipStream_t stream) {
  const float* xs   = (const float*)d_in[0];
  const float* ms   = (const float*)d_in[1];
  const float* h0   = (const float*)d_in[2];
  const float* W_ih = (const float*)d_in[3];
  const float* b_ih = (const float*)d_in[4];
  const float* W_hh = (const float*)d_in[5];
  const float* b_hh = (const float*)d_in[6];
  const float* W_xh = (const float*)d_in[7];
  const float* b_xh = (const float*)d_in[8];
  const float* W_r  = (const float*)d_in[9];
  const float* b_r  = (const float*)d_in[10];

  char* ws = (char*)d_ws;
  size_t off = 0;
  _Float16* xs_h = (_Float16*)(ws + off); off += 67108864;   // [32768][1024] f16
  _Float16* wcat = (_Float16*)(ws + off); off += 8388608;    // [4096][1024] f16
  _Float16* whh  = (_Float16*)(ws + off); off += 6291456;    // [3072][1024] f16
  _Float16* wr   = (_Float16*)(ws + off); off += 2097152;    // [1024][1024] f16
  _Float16* xgh  = (_Float16*)(ws + off); off += 268435456;  // [32768][4096] f16
  _Float16* hx   = (_Float16*)(ws + off); off += 262144;     // [2][64][1024] f16 parity dbuf
  _Float16* rhx  = (_Float16*)(ws + off); off += 262144;     // [2][64][1024] f16 parity dbuf
  unsigned* ctr  = (unsigned*)(ws + off); off += 2048;       // 256 flags + 256 ready

  hipMemsetAsync(ctr, 0, 2048, stream);
  kconv<<<2048, 256, 0, stream>>>(xs, W_ih, W_xh, W_hh, W_r, h0,
                                  xs_h, wcat, whh, wr, hx);
  krec<<<256, 512, 0, stream>>>(xgh, ms, whh, wr, b_hh, b_r, h0,
                                (u64*)hx, (u64*)rhx, (float*)d_out, ctr,
                                xs_h, wcat, b_ih, b_xh, xgh);
}

// Round 14
// 4358.657 us; speedup vs baseline: 1.0928x; 1.0928x over previous
//
#include <hip/hip_runtime.h>
#include <stdint.h>

#define TSTEPS 512

typedef __attribute__((ext_vector_type(8))) _Float16 half8;
typedef __attribute__((ext_vector_type(4))) _Float16 half4;
typedef __attribute__((ext_vector_type(4))) float f32x4;
typedef __attribute__((ext_vector_type(4))) float float4v;
typedef unsigned long long u64;

static __device__ __forceinline__ float sigm(float x) { return 1.f / (1.f + __expf(-x)); }
static __device__ __forceinline__ float tanh_(float x) {
  x = fminf(15.f, fmaxf(-15.f, x));
  float e = __expf(-2.f * x);
  return (1.f - e) / (1.f + e);
}
static __device__ __forceinline__ half8 ld8(const _Float16* p) { return *(const half8*)p; }
static __device__ __forceinline__ f32x4 MFMA(half8 a, half8 b, f32x4 c) {
  return __builtin_amdgcn_mfma_f32_16x16x32_f16(a, b, c, 0, 0, 0);
}

// ---- MALL primitives (agent scope; proven r4/r5/r8/r12) ----
static __device__ __forceinline__ unsigned aadd(unsigned* p) {
  return __hip_atomic_fetch_add(p, 1u, __ATOMIC_RELAXED, __HIP_MEMORY_SCOPE_AGENT);
}
static __device__ __forceinline__ unsigned ald(const unsigned* p) {
  return __hip_atomic_load(p, __ATOMIC_RELAXED, __HIP_MEMORY_SCOPE_AGENT);
}
static __device__ __forceinline__ void ast(unsigned* p, unsigned v) {
  __hip_atomic_store(p, v, __ATOMIC_RELAXED, __HIP_MEMORY_SCOPE_AGENT);
}
struct U64x2 { u64 x, y; };
static __device__ __forceinline__ half8 ld_msg16(const u64* p) {
  u64 a = __hip_atomic_load(p,     __ATOMIC_RELAXED, __HIP_MEMORY_SCOPE_AGENT);
  u64 b = __hip_atomic_load(p + 1, __ATOMIC_RELAXED, __HIP_MEMORY_SCOPE_AGENT);
  U64x2 u{a, b};
  return __builtin_bit_cast(half8, u);
}
static __device__ __forceinline__ void st_msg(u64* p, u64 v) {
  __hip_atomic_store(p, v, __ATOMIC_RELAXED, __HIP_MEMORY_SCOPE_AGENT);
}
static __device__ __forceinline__ void wait_flags(const unsigned* line, unsigned tag) {
  const unsigned* p = line + (threadIdx.x & 31);
  while (!__all(ald(p) >= tag))
    __builtin_amdgcn_s_sleep(1);
  asm volatile("" ::: "memory");
}
static __device__ __forceinline__ void wait_blk(const unsigned* r) {
  while (ald(r) < 32u) __builtin_amdgcn_s_sleep(4);
  asm volatile("" ::: "memory");
}
// 16B write-through to MALL (cross-XCD visible; 32x fewer transactions than shorts)
static __device__ __forceinline__ void st16_wt(_Float16* p, half8 v) {
  asm volatile("global_store_dwordx4 %0, %1, off sc0 sc1" :: "v"(p), "v"(v) : "memory");
}

// ---------------- f32 -> f16 conversion / init (r8-identical) ----------------
__global__ __launch_bounds__(256) void kconv(
    const float* __restrict__ xs, const float* __restrict__ wih,
    const float* __restrict__ wxh, const float* __restrict__ whhf,
    const float* __restrict__ wrf, const float* __restrict__ h0,
    _Float16* __restrict__ xs_h, _Float16* __restrict__ wcat,
    _Float16* __restrict__ whh, _Float16* __restrict__ wr,
    _Float16* __restrict__ hx) {
  const long n1 = 8388608;   // xs / 4
  const long n2 = 1048576;   // wcat / 4
  const long n3 = 786432;    // whh / 4
  const long n4 = 262144;    // wr / 4
  const long n5 = 16384;     // h0 / 4 -> hx parity-0
  const long total = n1 + n2 + n3 + n4 + n5;
  for (long i = (long)blockIdx.x * 256 + threadIdx.x; i < total; i += (long)gridDim.x * 256) {
    const float* s; _Float16* d;
    if (i < n1) { s = xs + i * 4; d = xs_h + i * 4; }
    else if (i < n1 + n2) {
      long e = (i - n1) * 4;
      s = (e < 3145728) ? (wih + e) : (wxh + (e - 3145728));
      d = wcat + e;
    } else if (i < n1 + n2 + n3) { long e = (i - n1 - n2) * 4; s = whhf + e; d = whh + e; }
    else if (i < n1 + n2 + n3 + n4) { long e = (i - n1 - n2 - n3) * 4; s = wrf + e; d = wr + e; }
    else { long e = (i - n1 - n2 - n3 - n4) * 4; s = h0 + e; d = hx + e; }
    float4v v = *(const float4v*)s;
    half4 o = { (_Float16)v.x, (_Float16)v.y, (_Float16)v.z, (_Float16)v.w };
    *(half4*)d = o;
  }
}

// ---------------- gemm half: 8192 tiles, bm-major; LDS-staged coalesced C ----------------
static __device__ void run_gemm(
    int tid, int gw,
    const _Float16* __restrict__ X, const _Float16* __restrict__ W,
    const float* __restrict__ b_ih, const float* __restrict__ b_xh,
    _Float16* __restrict__ C, unsigned* __restrict__ ready,
    char* smem) {
  const int half = tid >> 8;         // two independent 256-thread tile engines
  const int htid = tid & 255;
  const int lane = htid & 63;
  const int w4 = htid >> 6;
  const int wm = (w4 >> 1) * 64, wn = (w4 & 1) * 64;
  const int arow = htid >> 2;
  const int kk8 = (htid & 3) * 8;
  const int fr = lane & 15, fq = lane >> 4;
  _Float16* as = (_Float16*)(smem + half * 55296);
  _Float16* bs = as + 5120;
  _Float16* cs = bs + 5120;          // 128 x 136 halves (pitch-padded, swizzled)
  const f32x4 zero = {0.f, 0.f, 0.f, 0.f};

  for (int i = 0; i < 32; ++i) {
    const int j = gw * 2 + half + 256 * i;   // bm-major job order
    const int bm = j >> 5, bn = j & 31;
    const int rb = bm * 128, cb = bn * 128;
    f32x4 acc[4][4];
    #pragma unroll
    for (int a = 0; a < 4; a++)
      #pragma unroll
      for (int b = 0; b < 4; b++) acc[a][b] = zero;
    for (int kt = 0; kt < 1024; kt += 32) {
      __syncthreads();
      #pragma unroll
      for (int jj = 0; jj < 2; jj++) {
        int r = jj * 64 + arow;
        *(half8*)(as + r * 40 + kk8) = ld8(X + (size_t)(rb + r) * 1024 + kt + kk8);
        *(half8*)(bs + r * 40 + kk8) = ld8(W + (size_t)(cb + r) * 1024 + kt + kk8);
      }
      __syncthreads();
      half8 af[4], bfr[4];
      #pragma unroll
      for (int q = 0; q < 4; q++) {
        af[q]  = *(const half8*)(as + (wm + q * 16 + fr) * 40 + fq * 8);
        bfr[q] = *(const half8*)(bs + (wn + q * 16 + fr) * 40 + fq * 8);
      }
      #pragma unroll
      for (int mi = 0; mi < 4; mi++)
        #pragma unroll
        for (int ni = 0; ni < 4; ni++)
          acc[mi][ni] = MFMA(af[mi], bfr[ni], acc[mi][ni]);
    }
    // stage C tile into LDS (bias fused, XOR swizzle to spread banks)
    #pragma unroll
    for (int mi = 0; mi < 4; mi++)
      #pragma unroll
      for (int ni = 0; ni < 4; ni++) {
        const int colL = wn + ni * 16 + fr;
        const int col = cb + colL;
        const float bias = (col < 3072) ? b_ih[col] : b_xh[col - 3072];
        #pragma unroll
        for (int r = 0; r < 4; r++) {
          const int row = wm + mi * 16 + fq * 4 + r;
          const int colS = colL ^ (((row >> 3) & 1) << 3);
          cs[row * 136 + colS] = (_Float16)(acc[mi][ni][r] + bias);
        }
      }
    __syncthreads();
    // coalesced 16B write-through stores (2048 transactions/tile vs 65536 shorts)
    #pragma unroll
    for (int p = 0; p < 8; p++) {
      const int idx = p * 256 + htid;
      const int row = idx >> 4, cg = idx & 15;
      const int cgs = cg ^ ((row >> 3) & 1);
      half8 v = *(const half8*)(cs + row * 136 + cgs * 8);
      st16_wt(C + (size_t)(rb + row) * 4096 + cb + cg * 8, v);
    }
    asm volatile("s_waitcnt vmcnt(0)" ::: "memory");   // C at MALL
    __syncthreads();
    if (htid == 0) (void)aadd(&ready[bm]);
  }
}

// ---------------- rec half: r8-proven protocol + xg ready-gating ----------------
#define RP 20
#define TP (16 * RP)

static __device__ void run_rec(
    int tid, int bid,
    const _Float16* __restrict__ xgh, const float* __restrict__ ms,
    const _Float16* __restrict__ whh, const _Float16* __restrict__ wr,
    const float* __restrict__ b_hh, const float* __restrict__ b_r,
    const float* __restrict__ h0,
    u64* __restrict__ hmsg, u64* __restrict__ rhmsg,
    float* __restrict__ out, unsigned* __restrict__ ctr,
    unsigned* __restrict__ ready, float* red) {
  const int lane = tid & 63, w = tid >> 6;
  const int fr = lane & 15, fq = lane >> 4;
  const int g = bid >> 5;
  const int slot = bid & 31;
  const int colbase = slot * 32;
  unsigned* flagA = ctr + (g * 2 + 0) * 32;   // rh(t) published => t+1
  unsigned* flagB = ctr + (g * 2 + 1) * 32;   // h(t) published  => t

  // weight fragments -> registers (unified VGPR/AGPR file keeps them resident)
  half8 wA[6][4], wB[2][4];
  #pragma unroll
  for (int nt = 0; nt < 6; nt++)
    #pragma unroll
    for (int ks = 0; ks < 4; ks++)
      wA[nt][ks] = ld8(whh + (size_t)((nt >> 1) * 1024 + colbase + (nt & 1) * 16 + fr) * 1024
                            + w * 128 + ks * 32 + fq * 8);
  #pragma unroll
  for (int nt = 0; nt < 2; nt++)
    #pragma unroll
    for (int ks = 0; ks < 4; ks++)
      wB[nt][ks] = ld8(wr + (size_t)(colbase + nt * 16 + fr) * 1024
                           + w * 128 + ks * 32 + fq * 8);

  const int b = tid >> 5, cc = tid & 31;
  const int gc = colbase + cc;
  const int gm = g * 16 + b;
  const float bhr = b_hh[gc], bhz = b_hh[1024 + gc], bhe = b_hh[2048 + gc];
  const float brr = b_r[gc];
  float hreg = h0[(size_t)gm * 1024 + gc];

  const u64* hcons = hmsg  + (g * 16 + fr) * 256 + w * 32 + fq * 2;
  const u64* rcons = rhmsg + (g * 16 + fr) * 256 + w * 32 + fq * 2;
  u64* hprod = hmsg  + gm * 256 + (gc >> 2);
  u64* rprod = rhmsg + gm * 256 + (gc >> 2);

  const f32x4 zero = {0.f, 0.f, 0.f, 0.f};

  // gated initial prefetch (needs xgh block 0)
  float pxr, pxz, pxe, pxh, ptm;
  wait_blk(&ready[0]);
  {
    const _Float16* xp = xgh + (size_t)gm * 4096;
    pxr = (float)xp[gc]; pxz = (float)xp[1024 + gc];
    pxe = (float)xp[2048 + gc]; pxh = (float)xp[3072 + gc];
    ptm = tanh_(ms[(size_t)gm * 1024 + gc]);
  }

  #pragma clang loop unroll(disable)
  for (int t = 0; t < TSTEPS; t++) {
    const int ph = t & 1;
    // ======== phase A: h(t) -> gates; publish rh(t)
    wait_flags(flagB, (unsigned)t);
    half8 av[4];
    #pragma unroll
    for (int ks = 0; ks < 4; ks++)
      av[ks] = ld_msg16(hcons + ph * 16384 + ks * 8);
    f32x4 accA[6];
    #pragma unroll
    for (int nt = 0; nt < 6; nt++) accA[nt] = zero;
    #pragma unroll
    for (int ks = 0; ks < 4; ks++)
      #pragma unroll
      for (int nt = 0; nt < 6; nt++)
        accA[nt] = MFMA(av[ks], wA[nt][ks], accA[nt]);
    #pragma unroll
    for (int nt = 0; nt < 6; nt++)
      #pragma unroll
      for (int r = 0; r < 4; r++)
        red[(w * 6 + nt) * TP + (fq * 4 + r) * RP + fr] = accA[nt][r];
    __syncthreads();                            // S1
    float sr = pxr + bhr, sz = pxz + bhz, se = pxe + bhe;
    {
      const int boff = b * RP + (cc & 15) + (cc >> 4) * TP;
      #pragma unroll
      for (int w8 = 0; w8 < 8; w8++) {
        const float* rp = red + w8 * 6 * TP + boff;
        sr += rp[0]; sz += rp[2 * TP]; se += rp[4 * TP];
      }
    }
    float rg = sigm(sr);
    float zz = sigm(sz), ee = sigm(se);
    {
      float rv = rg * hreg;
      unsigned us = (unsigned)(unsigned short)__builtin_bit_cast(unsigned short, (_Float16)rv);
      unsigned v01 = us | (((unsigned)__shfl_down((int)us, 1) & 0xFFFFu) << 16);
      unsigned v23 = (unsigned)__shfl_down((int)v01, 2);
      if (!(cc & 3))
        st_msg(rprod + ph * 16384, ((u64)v23 << 32) | (u64)v01);
    }
    asm volatile("s_waitcnt vmcnt(0)" ::: "memory");
    __syncthreads();                            // S2: rh acked (+red guard)
    if (tid == 0)
      ast(flagA + slot, (unsigned)(t + 1));
    // overlap window: gated prefetch of next step's xg/ms
    float nxr = 0.f, nxz = 0.f, nxe = 0.f, nxh = 0.f, ntm = 0.f;
    if (t + 1 < TSTEPS) {
      wait_blk(&ready[(t + 1) >> 1]);
      const _Float16* xp = xgh + (size_t)((t + 1) * 64 + gm) * 4096;
      nxr = (float)xp[gc]; nxz = (float)xp[1024 + gc];
      nxe = (float)xp[2048 + gc]; nxh = (float)xp[3072 + gc];
      ntm = tanh_(ms[(size_t)(t + 1) * 65536 + gm * 1024 + gc]);
    }
    wait_flags(flagA, (unsigned)(t + 1));

    // ======== phase B: rh(t) -> hhat; h update; publish h(t+1)
    half8 bv[4];
    #pragma unroll
    for (int ks = 0; ks < 4; ks++)
      bv[ks] = ld_msg16(rcons + ph * 16384 + ks * 8);
    f32x4 accB[2];
    #pragma unroll
    for (int nt = 0; nt < 2; nt++) accB[nt] = zero;
    #pragma unroll
    for (int ks = 0; ks < 4; ks++)
      #pragma unroll
      for (int nt = 0; nt < 2; nt++)
        accB[nt] = MFMA(bv[ks], wB[nt][ks], accB[nt]);
    #pragma unroll
    for (int nt = 0; nt < 2; nt++)
      #pragma unroll
      for (int r = 0; r < 4; r++)
        red[(w * 6 + nt) * TP + (fq * 4 + r) * RP + fr] = accB[nt][r];
    __syncthreads();                            // S3
    float s = pxh + brr;
    {
      const int boff = b * RP + (cc & 15) + (cc >> 4) * TP;
      #pragma unroll
      for (int w8 = 0; w8 < 8; w8++) s += red[w8 * 6 * TP + boff];
    }
    float hh = tanh_(s);
    float hn = zz * hreg + (1.f - zz) * hh + ee * ptm;
    hreg = hn;
    {
      unsigned us = (unsigned)(unsigned short)__builtin_bit_cast(unsigned short, (_Float16)hn);
      unsigned v01 = us | (((unsigned)__shfl_down((int)us, 1) & 0xFFFFu) << 16);
      unsigned v23 = (unsigned)__shfl_down((int)v01, 2);
      if (!(cc & 3))
        st_msg(hprod + (ph ^ 1) * 16384, ((u64)v23 << 32) | (u64)v01);
    }
    asm volatile("s_waitcnt vmcnt(0)" ::: "memory");
    __syncthreads();                            // S4: h acked (+red guard)
    if (tid == 0)
      ast(flagB + slot, (unsigned)(t + 1));
    __builtin_nontemporal_store(hn, out + (size_t)t * 65536 + gm * 1024 + gc);
    pxr = nxr; pxz = nxz; pxe = nxe; pxh = nxh; ptm = ntm;
  }
  out[(size_t)TSTEPS * 65536 + gm * 1024 + gc] = hreg;
}

// ---------------- fused kernel: 128 rec wgs + 128 gemm wgs (union LDS) ----------------
__global__ __launch_bounds__(512, 2) void krec(
    const _Float16* __restrict__ xgh_c, const float* __restrict__ ms,
    const _Float16* __restrict__ whh, const _Float16* __restrict__ wr,
    const float* __restrict__ b_hh, const float* __restrict__ b_r,
    const float* __restrict__ h0,
    u64* __restrict__ hmsg, u64* __restrict__ rhmsg,
    float* __restrict__ out, unsigned* __restrict__ ctr,
    const _Float16* __restrict__ X, const _Float16* __restrict__ W,
    const float* __restrict__ b_ih, const float* __restrict__ b_xh,
    _Float16* __restrict__ xgh_w) {
  __shared__ __align__(16) char smem[110592];  // union: rec red 60KB | gemm 2x54KB
  const int tid = threadIdx.x;
  const int bid = (int)blockIdx.x;
  unsigned* ready = ctr + 256;                 // per-bm-block counters

  if (bid < 128) {
    run_rec(tid, bid, xgh_c, ms, whh, wr, b_hh, b_r, h0,
            hmsg, rhmsg, out, ctr, ready, (float*)smem);
  } else {
    run_gemm(tid, bid - 128, X, W, b_ih, b_xh, xgh_w, ready, smem);
  }
}

extern "C" void kernel_launch(void* const* d_in, const int* in_sizes, int n_in,
                              void* d_out, int out_size, void* d_ws, size_t ws_size,
                              hipStream_t stream) {
  const float* xs   = (const float*)d_in[0];
  const float* ms   = (const float*)d_in[1];
  const float* h0   = (const float*)d_in[2];
  const float* W_ih = (const float*)d_in[3];
  const float* b_ih = (const float*)d_in[4];
  const float* W_hh = (const float*)d_in[5];
  const float* b_hh = (const float*)d_in[6];
  const float* W_xh = (const float*)d_in[7];
  const float* b_xh = (const float*)d_in[8];
  const float* W_r  = (const float*)d_in[9];
  const float* b_r  = (const float*)d_in[10];

  char* ws = (char*)d_ws;
  size_t off = 0;
  _Float16* xs_h = (_Float16*)(ws + off); off += 67108864;   // [32768][1024] f16
  _Float16* wcat = (_Float16*)(ws + off); off += 8388608;    // [4096][1024] f16
  _Float16* whh  = (_Float16*)(ws + off); off += 6291456;    // [3072][1024] f16
  _Float16* wr   = (_Float16*)(ws + off); off += 2097152;    // [1024][1024] f16
  _Float16* xgh  = (_Float16*)(ws + off); off += 268435456;  // [32768][4096] f16
  _Float16* hx   = (_Float16*)(ws + off); off += 262144;     // [2][64][1024] f16 parity dbuf
  _Float16* rhx  = (_Float16*)(ws + off); off += 262144;     // [2][64][1024] f16 parity dbuf
  unsigned* ctr  = (unsigned*)(ws + off); off += 2048;       // 256 flags + 256 ready

  hipMemsetAsync(ctr, 0, 2048, stream);
  kconv<<<2048, 256, 0, stream>>>(xs, W_ih, W_xh, W_hh, W_r, h0,
                                  xs_h, wcat, whh, wr, hx);
  krec<<<256, 512, 0, stream>>>(xgh, ms, whh, wr, b_hh, b_r, h0,
                                (u64*)hx, (u64*)rhx, (float*)d_out, ctr,
                                xs_h, wcat, b_ih, b_xh, xgh);
}

// Round 15
// 4178.157 us; speedup vs baseline: 1.1400x; 1.0432x over previous
//
#include <hip/hip_runtime.h>
#include <stdint.h>

#define TSTEPS 512

typedef __attribute__((ext_vector_type(8))) _Float16 half8;
typedef __attribute__((ext_vector_type(4))) _Float16 half4;
typedef __attribute__((ext_vector_type(4))) float f32x4;
typedef __attribute__((ext_vector_type(4))) float float4v;
typedef unsigned long long u64;

static __device__ __forceinline__ float sigm(float x) { return 1.f / (1.f + __expf(-x)); }
static __device__ __forceinline__ float tanh_(float x) {
  x = fminf(15.f, fmaxf(-15.f, x));
  float e = __expf(-2.f * x);
  return (1.f - e) / (1.f + e);
}
static __device__ __forceinline__ half8 ld8(const _Float16* p) { return *(const half8*)p; }
static __device__ __forceinline__ f32x4 MFMA(half8 a, half8 b, f32x4 c) {
  return __builtin_amdgcn_mfma_f32_16x16x32_f16(a, b, c, 0, 0, 0);
}

// ---- MALL primitives (agent scope; proven r4/r5/r8/r12) ----
static __device__ __forceinline__ unsigned aadd(unsigned* p) {
  return __hip_atomic_fetch_add(p, 1u, __ATOMIC_RELAXED, __HIP_MEMORY_SCOPE_AGENT);
}
static __device__ __forceinline__ unsigned ald(const unsigned* p) {
  return __hip_atomic_load(p, __ATOMIC_RELAXED, __HIP_MEMORY_SCOPE_AGENT);
}
static __device__ __forceinline__ void ast(unsigned* p, unsigned v) {
  __hip_atomic_store(p, v, __ATOMIC_RELAXED, __HIP_MEMORY_SCOPE_AGENT);
}
struct U64x2 { u64 x, y; };
static __device__ __forceinline__ half8 ld_msg16(const u64* p) {
  u64 a = __hip_atomic_load(p,     __ATOMIC_RELAXED, __HIP_MEMORY_SCOPE_AGENT);
  u64 b = __hip_atomic_load(p + 1, __ATOMIC_RELAXED, __HIP_MEMORY_SCOPE_AGENT);
  U64x2 u{a, b};
  return __builtin_bit_cast(half8, u);
}
static __device__ __forceinline__ void st_msg(u64* p, u64 v) {
  __hip_atomic_store(p, v, __ATOMIC_RELAXED, __HIP_MEMORY_SCOPE_AGENT);
}
static __device__ __forceinline__ void wait_flags(const unsigned* line, unsigned tag) {
  const unsigned* p = line + (threadIdx.x & 31);
  while (!__all(ald(p) >= tag))
    __builtin_amdgcn_s_sleep(1);
  asm volatile("" ::: "memory");
}
static __device__ __forceinline__ void wait_blk(const unsigned* r) {
  while (ald(r) < 32u) __builtin_amdgcn_s_sleep(4);
  asm volatile("" ::: "memory");
}
// f16 write-through to MALL (cross-XCD visible without dirty-L2 hazard)
static __device__ __forceinline__ void st_f16_wt(_Float16* p, float v) {
  unsigned u = (unsigned)(unsigned short)__builtin_bit_cast(unsigned short, (_Float16)v);
  asm volatile("global_store_short %0, %1, off sc0 sc1" :: "v"(p), "v"(u) : "memory");
}

// ---------------- f32 -> f16 conversion / init (r8-identical) ----------------
__global__ __launch_bounds__(256) void kconv(
    const float* __restrict__ xs, const float* __restrict__ wih,
    const float* __restrict__ wxh, const float* __restrict__ whhf,
    const float* __restrict__ wrf, const float* __restrict__ h0,
    _Float16* __restrict__ xs_h, _Float16* __restrict__ wcat,
    _Float16* __restrict__ whh, _Float16* __restrict__ wr,
    _Float16* __restrict__ hx) {
  const long n1 = 8388608;   // xs / 4
  const long n2 = 1048576;   // wcat / 4
  const long n3 = 786432;    // whh / 4
  const long n4 = 262144;    // wr / 4
  const long n5 = 16384;     // h0 / 4 -> hx parity-0
  const long total = n1 + n2 + n3 + n4 + n5;
  for (long i = (long)blockIdx.x * 256 + threadIdx.x; i < total; i += (long)gridDim.x * 256) {
    const float* s; _Float16* d;
    if (i < n1) { s = xs + i * 4; d = xs_h + i * 4; }
    else if (i < n1 + n2) {
      long e = (i - n1) * 4;
      s = (e < 3145728) ? (wih + e) : (wxh + (e - 3145728));
      d = wcat + e;
    } else if (i < n1 + n2 + n3) { long e = (i - n1 - n2) * 4; s = whhf + e; d = whh + e; }
    else if (i < n1 + n2 + n3 + n4) { long e = (i - n1 - n2 - n3) * 4; s = wrf + e; d = wr + e; }
    else { long e = (i - n1 - n2 - n3 - n4) * 4; s = h0 + e; d = hx + e; }
    float4v v = *(const float4v*)s;
    half4 o = { (_Float16)v.x, (_Float16)v.y, (_Float16)v.z, (_Float16)v.w };
    *(half4*)d = o;
  }
}

// ---------------- gemm half: 8192 tiles (128x128), bm-major, ready counters ----------------
static __device__ void run_gemm(
    int tid, int gw,
    const _Float16* __restrict__ X, const _Float16* __restrict__ W,
    const float* __restrict__ b_ih, const float* __restrict__ b_xh,
    _Float16* __restrict__ C, unsigned* __restrict__ ready,
    unsigned* __restrict__ alldone,
    _Float16* As, _Float16* Bs) {
  const int half = tid >> 8;         // two independent 256-thread tile engines
  const int htid = tid & 255;
  const int lane = htid & 63;
  const int w4 = htid >> 6;
  const int wm = (w4 >> 1) * 64, wn = (w4 & 1) * 64;
  const int arow = htid >> 2;
  const int kk8 = (htid & 3) * 8;
  const int fr = lane & 15, fq = lane >> 4;
  _Float16* as = As + half * 5120;
  _Float16* bs = Bs + half * 5120;
  const f32x4 zero = {0.f, 0.f, 0.f, 0.f};

  for (int i = 0; i < 32; ++i) {
    const int j = gw * 2 + half + 256 * i;   // bm-major job order
    const int bm = j >> 5, bn = j & 31;
    const int rb = bm * 128, cb = bn * 128;
    f32x4 acc[4][4];
    #pragma unroll
    for (int a = 0; a < 4; a++)
      #pragma unroll
      for (int b = 0; b < 4; b++) acc[a][b] = zero;
    for (int kt = 0; kt < 1024; kt += 32) {
      __syncthreads();
      #pragma unroll
      for (int jj = 0; jj < 2; jj++) {
        int r = jj * 64 + arow;
        *(half8*)(as + r * 40 + kk8) = ld8(X + (size_t)(rb + r) * 1024 + kt + kk8);
        *(half8*)(bs + r * 40 + kk8) = ld8(W + (size_t)(cb + r) * 1024 + kt + kk8);
      }
      __syncthreads();
      half8 af[4], bfr[4];
      #pragma unroll
      for (int q = 0; q < 4; q++) {
        af[q]  = *(const half8*)(as + (wm + q * 16 + fr) * 40 + fq * 8);
        bfr[q] = *(const half8*)(bs + (wn + q * 16 + fr) * 40 + fq * 8);
      }
      #pragma unroll
      for (int mi = 0; mi < 4; mi++)
        #pragma unroll
        for (int ni = 0; ni < 4; ni++)
          acc[mi][ni] = MFMA(af[mi], bfr[ni], acc[mi][ni]);
    }
    #pragma unroll
    for (int mi = 0; mi < 4; mi++)
      #pragma unroll
      for (int ni = 0; ni < 4; ni++) {
        int col = cb + wn + ni * 16 + fr;
        float bias = (col < 3072) ? b_ih[col] : b_xh[col - 3072];
        #pragma unroll
        for (int r = 0; r < 4; r++) {
          int row = rb + wm + mi * 16 + fq * 4 + r;
          st_f16_wt(C + (size_t)row * 4096 + col, acc[mi][ni][r] + bias);
        }
      }
    asm volatile("s_waitcnt vmcnt(0)" ::: "memory");   // C at MALL
    __syncthreads();
    if (htid == 0) (void)aadd(&ready[bm]);
  }
  if (htid == 0) (void)aadd(alldone);   // engine complete (256 total)
}

// ---------------- rec half: r8-proven protocol + gated-until-done xg prefetch ----------------
#define RP 20
#define TP (16 * RP)

static __device__ void run_rec(
    int tid, int bid,
    const _Float16* __restrict__ xgh, const float* __restrict__ ms,
    const _Float16* __restrict__ whh, const _Float16* __restrict__ wr,
    const float* __restrict__ b_hh, const float* __restrict__ b_r,
    const float* __restrict__ h0,
    u64* __restrict__ hmsg, u64* __restrict__ rhmsg,
    float* __restrict__ out, unsigned* __restrict__ ctr,
    unsigned* __restrict__ ready, unsigned* __restrict__ alldone, float* red) {
  const int lane = tid & 63, w = tid >> 6;
  const int fr = lane & 15, fq = lane >> 4;
  const int g = bid >> 5;
  const int slot = bid & 31;
  const int colbase = slot * 32;
  unsigned* flagA = ctr + (g * 2 + 0) * 32;   // rh(t) published => t+1
  unsigned* flagB = ctr + (g * 2 + 1) * 32;   // h(t) published  => t

  // weight fragments -> registers (unified VGPR/AGPR file keeps them resident)
  half8 wA[6][4], wB[2][4];
  #pragma unroll
  for (int nt = 0; nt < 6; nt++)
    #pragma unroll
    for (int ks = 0; ks < 4; ks++)
      wA[nt][ks] = ld8(whh + (size_t)((nt >> 1) * 1024 + colbase + (nt & 1) * 16 + fr) * 1024
                            + w * 128 + ks * 32 + fq * 8);
  #pragma unroll
  for (int nt = 0; nt < 2; nt++)
    #pragma unroll
    for (int ks = 0; ks < 4; ks++)
      wB[nt][ks] = ld8(wr + (size_t)(colbase + nt * 16 + fr) * 1024
                           + w * 128 + ks * 32 + fq * 8);

  const int b = tid >> 5, cc = tid & 31;
  const int gc = colbase + cc;
  const int gm = g * 16 + b;
  const float bhr = b_hh[gc], bhz = b_hh[1024 + gc], bhe = b_hh[2048 + gc];
  const float brr = b_r[gc];
  float hreg = h0[(size_t)gm * 1024 + gc];

  const u64* hcons = hmsg  + (g * 16 + fr) * 256 + w * 32 + fq * 2;
  const u64* rcons = rhmsg + (g * 16 + fr) * 256 + w * 32 + fq * 2;
  u64* hprod = hmsg  + gm * 256 + (gc >> 2);
  u64* rprod = rhmsg + gm * 256 + (gc >> 2);

  const f32x4 zero = {0.f, 0.f, 0.f, 0.f};

  // gated initial prefetch (needs xgh block 0)
  float pxr, pxz, pxe, pxh, ptm;
  wait_blk(&ready[0]);
  {
    const _Float16* xp = xgh + (size_t)gm * 4096;
    pxr = (float)xp[gc]; pxz = (float)xp[1024 + gc];
    pxe = (float)xp[2048 + gc]; pxh = (float)xp[3072 + gc];
    ptm = tanh_(ms[(size_t)gm * 1024 + gc]);
  }
  int gdone = 0;

  #pragma clang loop unroll(disable)
  for (int t = 0; t < TSTEPS; t++) {
    const int ph = t & 1;
    // ======== phase A: h(t) -> gates; publish rh(t)
    wait_flags(flagB, (unsigned)t);
    half8 av[4];
    #pragma unroll
    for (int ks = 0; ks < 4; ks++)
      av[ks] = ld_msg16(hcons + ph * 16384 + ks * 8);
    f32x4 accA[6];
    #pragma unroll
    for (int nt = 0; nt < 6; nt++) accA[nt] = zero;
    #pragma unroll
    for (int ks = 0; ks < 4; ks++)
      #pragma unroll
      for (int nt = 0; nt < 6; nt++)
        accA[nt] = MFMA(av[ks], wA[nt][ks], accA[nt]);
    #pragma unroll
    for (int nt = 0; nt < 6; nt++)
      #pragma unroll
      for (int r = 0; r < 4; r++)
        red[(w * 6 + nt) * TP + (fq * 4 + r) * RP + fr] = accA[nt][r];
    __syncthreads();                            // S1
    float sr = pxr + bhr, sz = pxz + bhz, se = pxe + bhe;
    {
      const int boff = b * RP + (cc & 15) + (cc >> 4) * TP;
      #pragma unroll
      for (int w8 = 0; w8 < 8; w8++) {
        const float* rp = red + w8 * 6 * TP + boff;
        sr += rp[0]; sz += rp[2 * TP]; se += rp[4 * TP];
      }
    }
    float rg = sigm(sr);
    float zz = sigm(sz), ee = sigm(se);
    {
      float rv = rg * hreg;
      unsigned us = (unsigned)(unsigned short)__builtin_bit_cast(unsigned short, (_Float16)rv);
      unsigned v01 = us | (((unsigned)__shfl_down((int)us, 1) & 0xFFFFu) << 16);
      unsigned v23 = (unsigned)__shfl_down((int)v01, 2);
      if (!(cc & 3))
        st_msg(rprod + ph * 16384, ((u64)v23 << 32) | (u64)v01);
    }
    asm volatile("s_waitcnt vmcnt(0)" ::: "memory");
    __syncthreads();                            // S2: rh acked (+red guard)
    if (tid == 0)
      ast(flagA + slot, (unsigned)(t + 1));
    // overlap window: xg/ms prefetch; production gate vanishes once gemm done
    float nxr = 0.f, nxz = 0.f, nxe = 0.f, nxh = 0.f, ntm = 0.f;
    if (t + 1 < TSTEPS) {
      if (!gdone) {
        unsigned ad = ald(alldone);             // parallel with the ready load
        wait_blk(&ready[(t + 1) >> 1]);
        if (ad >= 256u) gdone = 1;
      }
      const _Float16* xp = xgh + (size_t)((t + 1) * 64 + gm) * 4096;
      nxr = (float)xp[gc]; nxz = (float)xp[1024 + gc];
      nxe = (float)xp[2048 + gc]; nxh = (float)xp[3072 + gc];
      ntm = tanh_(ms[(size_t)(t + 1) * 65536 + gm * 1024 + gc]);
    }
    wait_flags(flagA, (unsigned)(t + 1));

    // ======== phase B: rh(t) -> hhat; h update; publish h(t+1)
    half8 bv[4];
    #pragma unroll
    for (int ks = 0; ks < 4; ks++)
      bv[ks] = ld_msg16(rcons + ph * 16384 + ks * 8);
    f32x4 accB[2];
    #pragma unroll
    for (int nt = 0; nt < 2; nt++) accB[nt] = zero;
    #pragma unroll
    for (int ks = 0; ks < 4; ks++)
      #pragma unroll
      for (int nt = 0; nt < 2; nt++)
        accB[nt] = MFMA(bv[ks], wB[nt][ks], accB[nt]);
    #pragma unroll
    for (int nt = 0; nt < 2; nt++)
      #pragma unroll
      for (int r = 0; r < 4; r++)
        red[(w * 6 + nt) * TP + (fq * 4 + r) * RP + fr] = accB[nt][r];
    __syncthreads();                            // S3
    float s = pxh + brr;
    {
      const int boff = b * RP + (cc & 15) + (cc >> 4) * TP;
      #pragma unroll
      for (int w8 = 0; w8 < 8; w8++) s += red[w8 * 6 * TP + boff];
    }
    float hh = tanh_(s);
    float hn = zz * hreg + (1.f - zz) * hh + ee * ptm;
    hreg = hn;
    {
      unsigned us = (unsigned)(unsigned short)__builtin_bit_cast(unsigned short, (_Float16)hn);
      unsigned v01 = us | (((unsigned)__shfl_down((int)us, 1) & 0xFFFFu) << 16);
      unsigned v23 = (unsigned)__shfl_down((int)v01, 2);
      if (!(cc & 3))
        st_msg(hprod + (ph ^ 1) * 16384, ((u64)v23 << 32) | (u64)v01);
    }
    asm volatile("s_waitcnt vmcnt(0)" ::: "memory");
    __syncthreads();                            // S4: h acked (+red guard)
    if (tid == 0)
      ast(flagB + slot, (unsigned)(t + 1));
    __builtin_nontemporal_store(hn, out + (size_t)t * 65536 + gm * 1024 + gc);
    pxr = nxr; pxz = nxz; pxe = nxe; pxh = nxh; ptm = ntm;
  }
  out[(size_t)TSTEPS * 65536 + gm * 1024 + gc] = hreg;
}

// ---------------- fused kernel: 128 rec wgs + 128 gemm wgs ----------------
__global__ __launch_bounds__(512, 2) void krec(
    const _Float16* __restrict__ xgh_c, const float* __restrict__ ms,
    const _Float16* __restrict__ whh, const _Float16* __restrict__ wr,
    const float* __restrict__ b_hh, const float* __restrict__ b_r,
    const float* __restrict__ h0,
    u64* __restrict__ hmsg, u64* __restrict__ rhmsg,
    float* __restrict__ out, unsigned* __restrict__ ctr,
    const _Float16* __restrict__ X, const _Float16* __restrict__ W,
    const float* __restrict__ b_ih, const float* __restrict__ b_xh,
    _Float16* __restrict__ xgh_w) {
  __shared__ float red[48 * TP];                 // 60 KiB (rec)
  __shared__ _Float16 As[2 * 5120], Bs[2 * 5120]; // 40 KiB (gemm)
  const int tid = threadIdx.x;
  const int bid = (int)blockIdx.x;
  unsigned* ready = ctr + 256;                   // per-bm-block counters
  unsigned* alldone = ctr + 512;                 // gemm engines complete

  if (bid < 128) {
    run_rec(tid, bid, xgh_c, ms, whh, wr, b_hh, b_r, h0,
            hmsg, rhmsg, out, ctr, ready, alldone, red);
  } else {
    run_gemm(tid, bid - 128, X, W, b_ih, b_xh, xgh_w, ready, alldone, As, Bs);
  }
}

extern "C" void kernel_launch(void* const* d_in, const int* in_sizes, int n_in,
                              void* d_out, int out_size, void* d_ws, size_t ws_size,
                              hipStream_t stream) {
  const float* xs   = (const float*)d_in[0];
  const float* ms   = (const float*)d_in[1];
  const float* h0   = (const float*)d_in[2];
  const float* W_ih = (const float*)d_in[3];
  const float* b_ih = (const float*)d_in[4];
  const float* W_hh = (const float*)d_in[5];
  const float* b_hh = (const float*)d_in[6];
  const float* W_xh = (const float*)d_in[7];
  const float* b_xh = (const float*)d_in[8];
  const float* W_r  = (const float*)d_in[9];
  const float* b_r  = (const float*)d_in[10];

  char* ws = (char*)d_ws;
  size_t off = 0;
  _Float16* xs_h = (_Float16*)(ws + off); off += 67108864;   // [32768][1024] f16
  _Float16* wcat = (_Float16*)(ws + off); off += 8388608;    // [4096][1024] f16
  _Float16* whh  = (_Float16*)(ws + off); off += 6291456;    // [3072][1024] f16
  _Float16* wr   = (_Float16*)(ws + off); off += 2097152;    // [1024][1024] f16
  _Float16* xgh  = (_Float16*)(ws + off); off += 268435456;  // [32768][4096] f16
  _Float16* hx   = (_Float16*)(ws + off); off += 262144;     // [2][64][1024] f16 parity dbuf
  _Float16* rhx  = (_Float16*)(ws + off); off += 262144;     // [2][64][1024] f16 parity dbuf
  unsigned* ctr  = (unsigned*)(ws + off); off += 4096;       // 256 flags + 256 ready + alldone

  hipMemsetAsync(ctr, 0, 4096, stream);
  kconv<<<2048, 256, 0, stream>>>(xs, W_ih, W_xh, W_hh, W_r, h0,
                                  xs_h, wcat, whh, wr, hx);
  krec<<<256, 512, 0, stream>>>(xgh, ms, whh, wr, b_hh, b_r, h0,
                                (u64*)hx, (u64*)rhx, (float*)d_out, ctr,
                                xs_h, wcat, b_ih, b_xh, xgh);
}